// Round 9
// baseline (414.462 us; speedup 1.0000x reference)
//
#include <hip/hip_runtime.h>

constexpr int NNODES = 50000;
constexpr int NEDGES = 600000;
constexpr int NGRAPH = 2000;
constexpr int F0     = 64;    // IN_FEATS
constexpr int H      = 128;   // HIDDEN
constexpr int H2     = 256;   // 2*HIDDEN
constexpr int NB     = 49;    // scan blocks: 49*1024 >= 50000

static __device__ __forceinline__ void fma4(float4& acc, float s, const float4& w) {
    acc.x = fmaf(s, w.x, acc.x);
    acc.y = fmaf(s, w.y, acc.y);
    acc.z = fmaf(s, w.z, acc.z);
    acc.w = fmaf(s, w.w, acc.w);
}

// ---------------- degree count + per-edge rank: 1 edge/thread (max TLP) ----------------
__global__ void k_deg(const int* __restrict__ src, const int* __restrict__ dst,
                      int* __restrict__ dout, int* __restrict__ din,
                      int* __restrict__ rank) {
    int e = blockIdx.x * 256 + threadIdx.x;
    if (e < NEDGES) {
        int d = dst[e];
        int s = src[e];
        rank[e] = atomicAdd(&din[d], 1);
        atomicAdd(&dout[s], 1);
    }
}

// ---------------- scan phase 1: per-block scan of deg_in; also c_in ----------------
__global__ __launch_bounds__(1024) void k_scan1(const int* __restrict__ deg,
                                                int* __restrict__ row_start,
                                                int* __restrict__ partials,
                                                float* __restrict__ c_in) {
    __shared__ int wsum[16];
    int idx  = blockIdx.x * 1024 + threadIdx.x;
    int lane = threadIdx.x & 63;
    int wid  = threadIdx.x >> 6;
    int v = (idx < NNODES) ? deg[idx] : 0;
    if (idx < NNODES) c_in[idx] = rsqrtf(fmaxf((float)v, 1.0f));
    int incl = v;
#pragma unroll
    for (int off = 1; off < 64; off <<= 1) {
        int t = __shfl_up(incl, off);
        if (lane >= off) incl += t;
    }
    if (lane == 63) wsum[wid] = incl;
    __syncthreads();
    if (wid == 0) {
        int w = (lane < 16) ? wsum[lane] : 0;
        int wincl = w;
#pragma unroll
        for (int off = 1; off < 16; off <<= 1) {
            int t = __shfl_up(wincl, off);
            if (lane >= off) wincl += t;
        }
        if (lane < 16) wsum[lane] = wincl - w;
    }
    __syncthreads();
    int excl = wsum[wid] + incl - v;
    if (idx < NNODES) row_start[idx] = excl;
    if (threadIdx.x == 1023) partials[blockIdx.x] = excl + v;
}

// ---------------- scan phase 2 (fused): block offsets + sentinel + c_out + gbounds ----------------
__global__ __launch_bounds__(1024) void k_scan3(int* __restrict__ row_start,
                                                const int* __restrict__ partials,
                                                const int* __restrict__ dout,
                                                float* __restrict__ c_out,
                                                const int* __restrict__ gids,
                                                int* __restrict__ gstart) {
    __shared__ int soff[2];
    if (threadIdx.x < 64) {
        int lane = threadIdx.x;
        int v = (lane < NB) ? partials[lane] : 0;
        int incl = v;
#pragma unroll
        for (int off = 1; off < 64; off <<= 1) {
            int t = __shfl_up(incl, off);
            if (lane >= off) incl += t;
        }
        if (lane == (int)blockIdx.x) soff[0] = incl - v;
        if (lane == NB - 1) soff[1] = incl;
    }
    __syncthreads();
    int idx = blockIdx.x * 1024 + threadIdx.x;
    if (idx < NNODES) {
        row_start[idx] += soff[0];
        c_out[idx] = rsqrtf(fmaxf((float)dout[idx], 1.0f));
    } else if (idx == NNODES) {
        row_start[NNODES] = soff[1];
    }
    if (idx == 0) {
        int g0 = gids[0];
        for (int g = 0; g <= g0; ++g) gstart[g] = 0;
    } else if (idx == NNODES) {
        int gl = gids[NNODES - 1];
        for (int g = gl + 1; g <= NGRAPH; ++g) gstart[g] = NNODES;
    } else if (idx < NNODES) {
        int a = gids[idx - 1], b = gids[idx];
        for (int g = a + 1; g <= b; ++g) gstart[g] = idx;
    }
}

// ---------------- fill CSR: atomic-free (rank precomputed) ----------------
__global__ void k_fill(const int* __restrict__ src, const int* __restrict__ dst,
                       const int* __restrict__ row_start, const int* __restrict__ rank,
                       int* __restrict__ csr_src) {
    int t = blockIdx.x * 256 + threadIdx.x;
    if (t * 4 >= NEDGES) return;
    int4 s4 = ((const int4*)src)[t];
    int4 d4 = ((const int4*)dst)[t];
    int4 r4 = ((const int4*)rank)[t];
    csr_src[row_start[d4.x] + r4.x] = s4.x;
    csr_src[row_start[d4.y] + r4.y] = s4.y;
    csr_src[row_start[d4.z] + r4.z] = s4.z;
    csr_src[row_start[d4.w] + r4.w] = s4.w;
}

// ---------------- gather: layer 1 (F=64, with c_out) ----------------
__global__ __launch_bounds__(256) void k_gather1(const float* __restrict__ x,
                                                 const float* __restrict__ c_out,
                                                 const int* __restrict__ row_start,
                                                 const int* __restrict__ csr_src,
                                                 float* __restrict__ agg) {
    int wid  = (blockIdx.x * 256 + threadIdx.x) >> 6;
    int lane = threadIdx.x & 63;
    if (wid >= NNODES) return;
    int beg = row_start[wid], end = row_start[wid + 1];
    float acc = 0.f;
#pragma unroll 4
    for (int i = beg; i < end; ++i) {
        int s = csr_src[i];
        acc += x[(long)s * F0 + lane] * c_out[s];
    }
    agg[(long)wid * F0 + lane] = acc;
}

// ---------------- gather: layers 2/3 (F=128, input pre-scaled by c_out) ----------------
static __device__ __forceinline__ void gather_h_body(const float* __restrict__ x,
                                                     const int* __restrict__ row_start,
                                                     const int* __restrict__ csr_src,
                                                     float* __restrict__ agg) {
    int wid  = (blockIdx.x * 256 + threadIdx.x) >> 6;
    int lane = threadIdx.x & 63;
    if (wid >= NNODES) return;
    int beg = row_start[wid], end = row_start[wid + 1];
    const float2* x2 = (const float2*)x;
    float2 acc = make_float2(0.f, 0.f);
#pragma unroll 4
    for (int i = beg; i < end; ++i) {
        int s = csr_src[i];
        float2 v = x2[(long)s * 64 + lane];
        acc.x += v.x;
        acc.y += v.y;
    }
    ((float2*)agg)[(long)wid * 64 + lane] = acc;
}

__global__ __launch_bounds__(256) void k_gather2(const float* __restrict__ x,
                                                 const int* __restrict__ row_start,
                                                 const int* __restrict__ csr_src,
                                                 float* __restrict__ agg) {
    gather_h_body(x, row_start, csr_src, agg);
}
__global__ __launch_bounds__(256) void k_gather3(const float* __restrict__ x,
                                                 const int* __restrict__ row_start,
                                                 const int* __restrict__ csr_src,
                                                 float* __restrict__ agg) {
    gather_h_body(x, row_start, csr_src, agg);
}

// ---------------- register-blocked fused GEMM (64-row tile, 256 threads) ----------------
// out[n][j] = act( c_in[n]*(A@W)[n][j] + b[j] ) * (COSCALE ? c_out[n] : 1)
template <int K, bool RELU, bool COSCALE>
static __device__ __forceinline__ void gemm_body(const float* __restrict__ A,
                                                 const float* __restrict__ c_in,
                                                 const float* __restrict__ c_out,
                                                 const float* __restrict__ W,
                                                 const float* __restrict__ b,
                                                 float* __restrict__ out) {
    __shared__ float sW[K * H];
    for (int i = threadIdx.x; i < K * (H / 4); i += 256)
        ((float4*)sW)[i] = ((const float4*)W)[i];
    __syncthreads();

    const int c = threadIdx.x & 31;   // col quad
    const int r = threadIdx.x >> 5;   // row octet (0..7)
    const long base = (long)blockIdx.x * 64 + r * 8;

    float4 acc[8];
#pragma unroll
    for (int i = 0; i < 8; ++i) acc[i] = make_float4(0.f, 0.f, 0.f, 0.f);

    const float4* Ap = (const float4*)A + base * (K / 4);

    for (int k4 = 0; k4 < K / 4; ++k4) {
        const float4 w0 = *(const float4*)&sW[(4 * k4 + 0) * H + 4 * c];
        const float4 w1 = *(const float4*)&sW[(4 * k4 + 1) * H + 4 * c];
        const float4 w2 = *(const float4*)&sW[(4 * k4 + 2) * H + 4 * c];
        const float4 w3 = *(const float4*)&sW[(4 * k4 + 3) * H + 4 * c];
#pragma unroll
        for (int i = 0; i < 8; ++i) {
            float4 a = Ap[(long)i * (K / 4) + k4];
            fma4(acc[i], a.x, w0);
            fma4(acc[i], a.y, w1);
            fma4(acc[i], a.z, w2);
            fma4(acc[i], a.w, w3);
        }
    }

    const float4 bv = ((const float4*)b)[c];
#pragma unroll
    for (int i = 0; i < 8; ++i) {
        long n = base + i;
        if (n < NNODES) {
            float ci = c_in[n];
            float4 res;
            res.x = fmaf(acc[i].x, ci, bv.x);
            res.y = fmaf(acc[i].y, ci, bv.y);
            res.z = fmaf(acc[i].z, ci, bv.z);
            res.w = fmaf(acc[i].w, ci, bv.w);
            if (RELU) {
                res.x = fmaxf(res.x, 0.f);
                res.y = fmaxf(res.y, 0.f);
                res.z = fmaxf(res.z, 0.f);
                res.w = fmaxf(res.w, 0.f);
            }
            if (COSCALE) {
                float co = c_out[n];
                res.x *= co; res.y *= co; res.z *= co; res.w *= co;
            }
            ((float4*)out)[n * (H / 4) + c] = res;
        }
    }
}

__global__ __launch_bounds__(256) void k_gemm1(const float* __restrict__ A,
                                               const float* __restrict__ c_in,
                                               const float* __restrict__ c_out,
                                               const float* __restrict__ W,
                                               const float* __restrict__ b,
                                               float* __restrict__ out) {
    gemm_body<F0, true, true>(A, c_in, c_out, W, b, out);
}
__global__ __launch_bounds__(256) void k_gemm2(const float* __restrict__ A,
                                               const float* __restrict__ c_in,
                                               const float* __restrict__ c_out,
                                               const float* __restrict__ W,
                                               const float* __restrict__ b,
                                               float* __restrict__ out) {
    gemm_body<H, true, true>(A, c_in, c_out, W, b, out);
}
__global__ __launch_bounds__(256) void k_gemm3(const float* __restrict__ A,
                                               const float* __restrict__ c_in,
                                               const float* __restrict__ c_out,
                                               const float* __restrict__ W,
                                               const float* __restrict__ b,
                                               float* __restrict__ out) {
    gemm_body<H, false, false>(A, c_in, c_out, W, b, out);
}

// ---------------- fused graph head: readout mean + 3-layer MLP ----------------
__global__ __launch_bounds__(512) void k_head(const float* __restrict__ y,
                                              const int* __restrict__ gstart,
                                              const float* __restrict__ fg,
                                              const float* __restrict__ Wl1,
                                              const float* __restrict__ bl1,
                                              const float* __restrict__ Wl2,
                                              const float* __restrict__ bl2,
                                              const float* __restrict__ Wl3,
                                              const float* __restrict__ bl3,
                                              float* __restrict__ out) {
    __shared__ float smean[8][H];
    __shared__ float sh1[8][H2];
    __shared__ float sh2[8][H2];

    const int w    = threadIdx.x >> 6;
    const int lane = threadIdx.x & 63;
    const int g    = blockIdx.x * 8 + w;

    {
        int beg = gstart[g], end = gstart[g + 1];
        const float2* y2 = (const float2*)y;
        float2 acc = make_float2(0.f, 0.f);
        for (int n = beg; n < end; ++n) {
            float2 v = y2[(long)n * 64 + lane];
            acc.x += v.x;
            acc.y += v.y;
        }
        float inv = 1.0f / fmaxf((float)(end - beg), 1.0f);
        ((float2*)smean[w])[lane] = make_float2(acc.x * inv, acc.y * inv);
    }

    {
        float4 acc = ((const float4*)bl1)[lane];
        for (int k = 0; k < H; ++k)
            fma4(acc, smean[w][k], ((const float4*)(Wl1 + (long)k * H2))[lane]);
#pragma unroll
        for (int k = 0; k < 3; ++k)
            fma4(acc, fg[g * 3 + k], ((const float4*)(Wl1 + (long)(H + k) * H2))[lane]);
        acc.x = fmaxf(acc.x, 0.f); acc.y = fmaxf(acc.y, 0.f);
        acc.z = fmaxf(acc.z, 0.f); acc.w = fmaxf(acc.w, 0.f);
        ((float4*)sh1[w])[lane] = acc;
    }

    {
        float4 acc = ((const float4*)bl2)[lane];
        for (int k = 0; k < H2; ++k)
            fma4(acc, sh1[w][k], ((const float4*)(Wl2 + (long)k * H2))[lane]);
        acc.x = fmaxf(acc.x, 0.f); acc.y = fmaxf(acc.y, 0.f);
        acc.z = fmaxf(acc.z, 0.f); acc.w = fmaxf(acc.w, 0.f);
        ((float4*)sh2[w])[lane] = acc;
    }

    {
        float sum = sh2[w][lane] * Wl3[lane]
                  + sh2[w][lane + 64] * Wl3[lane + 64]
                  + sh2[w][lane + 128] * Wl3[lane + 128]
                  + sh2[w][lane + 192] * Wl3[lane + 192];
        for (int off = 32; off; off >>= 1)
            sum += __shfl_down(sum, off);
        if (lane == 0) out[g] = sum + bl3[0];
    }
}

extern "C" void kernel_launch(void* const* d_in, const int* in_sizes, int n_in,
                              void* d_out, int out_size, void* d_ws, size_t ws_size,
                              hipStream_t stream) {
    const float* feats_node  = (const float*)d_in[0];
    const float* feats_graph = (const float*)d_in[1];
    const float* W1 = (const float*)d_in[2];
    const float* b1 = (const float*)d_in[3];
    const float* W2 = (const float*)d_in[4];
    const float* b2 = (const float*)d_in[5];
    const float* W3 = (const float*)d_in[6];
    const float* b3 = (const float*)d_in[7];
    const float* Wl1 = (const float*)d_in[8];
    const float* bl1 = (const float*)d_in[9];
    const float* Wl2 = (const float*)d_in[10];
    const float* bl2 = (const float*)d_in[11];
    const float* Wl3 = (const float*)d_in[12];
    const float* bl3 = (const float*)d_in[13];
    const int* src  = (const int*)d_in[14];
    const int* dst  = (const int*)d_in[15];
    const int* gids = (const int*)d_in[16];
    float* out = (float*)d_out;

    // workspace layout (4B units)
    float* ws = (float*)d_ws;
    float* c_out     = ws;                        // 50048
    float* c_in      = c_out + 50048;             // 50048
    float* A         = c_in + 50048;              // N*H
    float* B         = A + (size_t)NNODES * H;    // N*H
    int*   row_start = (int*)(B + (size_t)NNODES * H);  // 50176
    int*   csr_src   = row_start + 50176;         // 600000
    int*   gstart    = csr_src + NEDGES;          // 2048
    int*   partials  = gstart + 2048;             // 64
    int*   dout      = partials + 64;             // 50048
    int*   din       = dout + 50048;              // 50048
    int*   rank      = (int*)A;                   // aliases A (consumed before gather1 writes A)

    // degrees + edge ranks
    hipMemsetAsync(dout, 0, 2 * 50048 * sizeof(int), stream);
    k_deg<<<(NEDGES + 255) / 256, 256, 0, stream>>>(src, dst, dout, din, rank);

    // CSR offsets + c_in/c_out/gstart + atomic-free fill
    k_scan1<<<NB, 1024, 0, stream>>>(din, row_start, partials, c_in);
    k_scan3<<<NB, 1024, 0, stream>>>(row_start, partials, dout, c_out, gids, gstart);
    k_fill<<<(NEDGES / 4 + 255) / 256, 256, 0, stream>>>(src, dst, row_start, rank, csr_src);

    const int GEMM_GRID = (NNODES + 63) / 64;

    // layer 1
    k_gather1<<<NNODES / 4, 256, 0, stream>>>(feats_node, c_out, row_start, csr_src, A);
    k_gemm1<<<GEMM_GRID, 256, 0, stream>>>(A, c_in, c_out, W1, b1, B);

    // layer 2
    k_gather2<<<NNODES / 4, 256, 0, stream>>>(B, row_start, csr_src, A);
    k_gemm2<<<GEMM_GRID, 256, 0, stream>>>(A, c_in, c_out, W2, b2, B);

    // layer 3
    k_gather3<<<NNODES / 4, 256, 0, stream>>>(B, row_start, csr_src, A);
    k_gemm3<<<GEMM_GRID, 256, 0, stream>>>(A, c_in, c_out, W3, b3, B);

    // fused head
    k_head<<<NGRAPH / 8, 512, 0, stream>>>(B, gstart, feats_graph,
                                           Wl1, bl1, Wl2, bl2, Wl3, bl3, out);
}

// Round 10
// 407.987 us; speedup vs baseline: 1.0159x; 1.0159x over previous
//
#include <hip/hip_runtime.h>

constexpr int NNODES = 50000;
constexpr int NEDGES = 600000;
constexpr int NGRAPH = 2000;
constexpr int F0     = 64;    // IN_FEATS
constexpr int H      = 128;   // HIDDEN
constexpr int H2     = 256;   // 2*HIDDEN
constexpr int NB     = 49;    // scan blocks: 49*1024 >= 50000

static __device__ __forceinline__ void fma4(float4& acc, float s, const float4& w) {
    acc.x = fmaf(s, w.x, acc.x);
    acc.y = fmaf(s, w.y, acc.y);
    acc.z = fmaf(s, w.z, acc.z);
    acc.w = fmaf(s, w.w, acc.w);
}

// ---------------- degree count + per-edge rank (atomic-throughput floor ~52us) ----------------
__global__ void k_deg(const int* __restrict__ src, const int* __restrict__ dst,
                      int* __restrict__ dout, int* __restrict__ din,
                      int* __restrict__ rank) {
    int e = blockIdx.x * 256 + threadIdx.x;
    if (e < NEDGES) {
        int d = dst[e];
        int s = src[e];
        rank[e] = atomicAdd(&din[d], 1);
        atomicAdd(&dout[s], 1);
    }
}

// ---------------- scan phase 1: per-block scan of deg_in; also c_in ----------------
__global__ __launch_bounds__(1024) void k_scan1(const int* __restrict__ deg,
                                                int* __restrict__ row_start,
                                                int* __restrict__ partials,
                                                float* __restrict__ c_in) {
    __shared__ int wsum[16];
    int idx  = blockIdx.x * 1024 + threadIdx.x;
    int lane = threadIdx.x & 63;
    int wid  = threadIdx.x >> 6;
    int v = (idx < NNODES) ? deg[idx] : 0;
    if (idx < NNODES) c_in[idx] = rsqrtf(fmaxf((float)v, 1.0f));
    int incl = v;
#pragma unroll
    for (int off = 1; off < 64; off <<= 1) {
        int t = __shfl_up(incl, off);
        if (lane >= off) incl += t;
    }
    if (lane == 63) wsum[wid] = incl;
    __syncthreads();
    if (wid == 0) {
        int w = (lane < 16) ? wsum[lane] : 0;
        int wincl = w;
#pragma unroll
        for (int off = 1; off < 16; off <<= 1) {
            int t = __shfl_up(wincl, off);
            if (lane >= off) wincl += t;
        }
        if (lane < 16) wsum[lane] = wincl - w;
    }
    __syncthreads();
    int excl = wsum[wid] + incl - v;
    if (idx < NNODES) row_start[idx] = excl;
    if (threadIdx.x == 1023) partials[blockIdx.x] = excl + v;
}

// ---------------- scan phase 2 (fused): block offsets + sentinel + c_out + gbounds ----------------
__global__ __launch_bounds__(1024) void k_scan3(int* __restrict__ row_start,
                                                const int* __restrict__ partials,
                                                const int* __restrict__ dout,
                                                float* __restrict__ c_out,
                                                const int* __restrict__ gids,
                                                int* __restrict__ gstart) {
    __shared__ int soff[2];
    if (threadIdx.x < 64) {
        int lane = threadIdx.x;
        int v = (lane < NB) ? partials[lane] : 0;
        int incl = v;
#pragma unroll
        for (int off = 1; off < 64; off <<= 1) {
            int t = __shfl_up(incl, off);
            if (lane >= off) incl += t;
        }
        if (lane == (int)blockIdx.x) soff[0] = incl - v;
        if (lane == NB - 1) soff[1] = incl;
    }
    __syncthreads();
    int idx = blockIdx.x * 1024 + threadIdx.x;
    if (idx < NNODES) {
        row_start[idx] += soff[0];
        c_out[idx] = rsqrtf(fmaxf((float)dout[idx], 1.0f));
    } else if (idx == NNODES) {
        row_start[NNODES] = soff[1];
    }
    if (idx == 0) {
        int g0 = gids[0];
        for (int g = 0; g <= g0; ++g) gstart[g] = 0;
    } else if (idx == NNODES) {
        int gl = gids[NNODES - 1];
        for (int g = gl + 1; g <= NGRAPH; ++g) gstart[g] = NNODES;
    } else if (idx < NNODES) {
        int a = gids[idx - 1], b = gids[idx];
        for (int g = a + 1; g <= b; ++g) gstart[g] = idx;
    }
}

// ---------------- fill CSR: atomic-free (rank precomputed) ----------------
__global__ void k_fill(const int* __restrict__ src, const int* __restrict__ dst,
                       const int* __restrict__ row_start, const int* __restrict__ rank,
                       int* __restrict__ csr_src) {
    int t = blockIdx.x * 256 + threadIdx.x;
    if (t * 4 >= NEDGES) return;
    int4 s4 = ((const int4*)src)[t];
    int4 d4 = ((const int4*)dst)[t];
    int4 r4 = ((const int4*)rank)[t];
    csr_src[row_start[d4.x] + r4.x] = s4.x;
    csr_src[row_start[d4.y] + r4.y] = s4.y;
    csr_src[row_start[d4.z] + r4.z] = s4.z;
    csr_src[row_start[d4.w] + r4.w] = s4.w;
}

// ---------------- gather layer 1 (F=64, with c_out), 4-deep pipelined ----------------
__global__ __launch_bounds__(256) void k_gather1(const float* __restrict__ x,
                                                 const float* __restrict__ c_out,
                                                 const int* __restrict__ row_start,
                                                 const int* __restrict__ csr_src,
                                                 float* __restrict__ agg) {
    int wid  = (blockIdx.x * 256 + threadIdx.x) >> 6;
    int lane = threadIdx.x & 63;
    if (wid >= NNODES) return;
    int beg = row_start[wid], end = row_start[wid + 1];
    float acc = 0.f;
    int i = beg;
    for (; i + 4 <= end; i += 4) {
        int s0 = csr_src[i + 0];
        int s1 = csr_src[i + 1];
        int s2 = csr_src[i + 2];
        int s3 = csr_src[i + 3];
        float c0 = c_out[s0], c1 = c_out[s1], c2 = c_out[s2], c3 = c_out[s3];
        float v0 = x[(long)s0 * F0 + lane];
        float v1 = x[(long)s1 * F0 + lane];
        float v2 = x[(long)s2 * F0 + lane];
        float v3 = x[(long)s3 * F0 + lane];
        acc += v0 * c0 + v1 * c1 + v2 * c2 + v3 * c3;
    }
    for (; i < end; ++i) {
        int s = csr_src[i];
        acc += x[(long)s * F0 + lane] * c_out[s];
    }
    agg[(long)wid * F0 + lane] = acc;
}

// ---------------- gather layers 2/3 (F=128, pre-scaled input), 4-deep pipelined ----------------
static __device__ __forceinline__ void gather_h_body(const float* __restrict__ x,
                                                     const int* __restrict__ row_start,
                                                     const int* __restrict__ csr_src,
                                                     float* __restrict__ agg) {
    int wid  = (blockIdx.x * 256 + threadIdx.x) >> 6;
    int lane = threadIdx.x & 63;
    if (wid >= NNODES) return;
    int beg = row_start[wid], end = row_start[wid + 1];
    const float2* x2 = (const float2*)x;
    float2 acc = make_float2(0.f, 0.f);
    int i = beg;
    for (; i + 4 <= end; i += 4) {
        int s0 = csr_src[i + 0];
        int s1 = csr_src[i + 1];
        int s2 = csr_src[i + 2];
        int s3 = csr_src[i + 3];
        float2 v0 = x2[(long)s0 * 64 + lane];
        float2 v1 = x2[(long)s1 * 64 + lane];
        float2 v2 = x2[(long)s2 * 64 + lane];
        float2 v3 = x2[(long)s3 * 64 + lane];
        acc.x += v0.x + v1.x + v2.x + v3.x;
        acc.y += v0.y + v1.y + v2.y + v3.y;
    }
    for (; i < end; ++i) {
        int s = csr_src[i];
        float2 v = x2[(long)s * 64 + lane];
        acc.x += v.x;
        acc.y += v.y;
    }
    ((float2*)agg)[(long)wid * 64 + lane] = acc;
}

__global__ __launch_bounds__(256) void k_gather2(const float* __restrict__ x,
                                                 const int* __restrict__ row_start,
                                                 const int* __restrict__ csr_src,
                                                 float* __restrict__ agg) {
    gather_h_body(x, row_start, csr_src, agg);
}
__global__ __launch_bounds__(256) void k_gather3(const float* __restrict__ x,
                                                 const int* __restrict__ row_start,
                                                 const int* __restrict__ csr_src,
                                                 float* __restrict__ agg) {
    gather_h_body(x, row_start, csr_src, agg);
}

// ---------------- register-blocked fused GEMM (128-row tile, 512 threads — R8 proven) ----------------
// out[n][j] = act( c_in[n]*(A@W)[n][j] + b[j] ) * (COSCALE ? c_out[n] : 1)
template <int K, bool RELU, bool COSCALE>
static __device__ __forceinline__ void gemm_body(const float* __restrict__ A,
                                                 const float* __restrict__ c_in,
                                                 const float* __restrict__ c_out,
                                                 const float* __restrict__ W,
                                                 const float* __restrict__ b,
                                                 float* __restrict__ out) {
    __shared__ float sW[K * H];
    for (int i = threadIdx.x; i < K * (H / 4); i += 512)
        ((float4*)sW)[i] = ((const float4*)W)[i];
    __syncthreads();

    const int c = threadIdx.x & 31;
    const int r = threadIdx.x >> 5;
    const long base = (long)blockIdx.x * 128 + r * 8;

    float4 acc[8];
#pragma unroll
    for (int i = 0; i < 8; ++i) acc[i] = make_float4(0.f, 0.f, 0.f, 0.f);

    const float4* Ap = (const float4*)A + base * (K / 4);

    for (int k4 = 0; k4 < K / 4; ++k4) {
        const float4 w0 = *(const float4*)&sW[(4 * k4 + 0) * H + 4 * c];
        const float4 w1 = *(const float4*)&sW[(4 * k4 + 1) * H + 4 * c];
        const float4 w2 = *(const float4*)&sW[(4 * k4 + 2) * H + 4 * c];
        const float4 w3 = *(const float4*)&sW[(4 * k4 + 3) * H + 4 * c];
#pragma unroll
        for (int i = 0; i < 8; ++i) {
            float4 a = Ap[(long)i * (K / 4) + k4];
            fma4(acc[i], a.x, w0);
            fma4(acc[i], a.y, w1);
            fma4(acc[i], a.z, w2);
            fma4(acc[i], a.w, w3);
        }
    }

    const float4 bv = ((const float4*)b)[c];
#pragma unroll
    for (int i = 0; i < 8; ++i) {
        long n = base + i;
        if (n < NNODES) {
            float ci = c_in[n];
            float4 res;
            res.x = fmaf(acc[i].x, ci, bv.x);
            res.y = fmaf(acc[i].y, ci, bv.y);
            res.z = fmaf(acc[i].z, ci, bv.z);
            res.w = fmaf(acc[i].w, ci, bv.w);
            if (RELU) {
                res.x = fmaxf(res.x, 0.f);
                res.y = fmaxf(res.y, 0.f);
                res.z = fmaxf(res.z, 0.f);
                res.w = fmaxf(res.w, 0.f);
            }
            if (COSCALE) {
                float co = c_out[n];
                res.x *= co; res.y *= co; res.z *= co; res.w *= co;
            }
            ((float4*)out)[n * (H / 4) + c] = res;
        }
    }
}

__global__ __launch_bounds__(512) void k_gemm1(const float* __restrict__ A,
                                               const float* __restrict__ c_in,
                                               const float* __restrict__ c_out,
                                               const float* __restrict__ W,
                                               const float* __restrict__ b,
                                               float* __restrict__ out) {
    gemm_body<F0, true, true>(A, c_in, c_out, W, b, out);
}
__global__ __launch_bounds__(512) void k_gemm2(const float* __restrict__ A,
                                               const float* __restrict__ c_in,
                                               const float* __restrict__ c_out,
                                               const float* __restrict__ W,
                                               const float* __restrict__ b,
                                               float* __restrict__ out) {
    gemm_body<H, true, true>(A, c_in, c_out, W, b, out);
}
__global__ __launch_bounds__(512) void k_gemm3(const float* __restrict__ A,
                                               const float* __restrict__ c_in,
                                               const float* __restrict__ c_out,
                                               const float* __restrict__ W,
                                               const float* __restrict__ b,
                                               float* __restrict__ out) {
    gemm_body<H, false, false>(A, c_in, c_out, W, b, out);
}

// ---------------- fused graph head: readout mean + 3-layer MLP ----------------
__global__ __launch_bounds__(512) void k_head(const float* __restrict__ y,
                                              const int* __restrict__ gstart,
                                              const float* __restrict__ fg,
                                              const float* __restrict__ Wl1,
                                              const float* __restrict__ bl1,
                                              const float* __restrict__ Wl2,
                                              const float* __restrict__ bl2,
                                              const float* __restrict__ Wl3,
                                              const float* __restrict__ bl3,
                                              float* __restrict__ out) {
    __shared__ float smean[8][H];
    __shared__ float sh1[8][H2];
    __shared__ float sh2[8][H2];

    const int w    = threadIdx.x >> 6;
    const int lane = threadIdx.x & 63;
    const int g    = blockIdx.x * 8 + w;

    {
        int beg = gstart[g], end = gstart[g + 1];
        const float2* y2 = (const float2*)y;
        float2 acc = make_float2(0.f, 0.f);
        for (int n = beg; n < end; ++n) {
            float2 v = y2[(long)n * 64 + lane];
            acc.x += v.x;
            acc.y += v.y;
        }
        float inv = 1.0f / fmaxf((float)(end - beg), 1.0f);
        ((float2*)smean[w])[lane] = make_float2(acc.x * inv, acc.y * inv);
    }

    {
        float4 acc = ((const float4*)bl1)[lane];
        for (int k = 0; k < H; ++k)
            fma4(acc, smean[w][k], ((const float4*)(Wl1 + (long)k * H2))[lane]);
#pragma unroll
        for (int k = 0; k < 3; ++k)
            fma4(acc, fg[g * 3 + k], ((const float4*)(Wl1 + (long)(H + k) * H2))[lane]);
        acc.x = fmaxf(acc.x, 0.f); acc.y = fmaxf(acc.y, 0.f);
        acc.z = fmaxf(acc.z, 0.f); acc.w = fmaxf(acc.w, 0.f);
        ((float4*)sh1[w])[lane] = acc;
    }

    {
        float4 acc = ((const float4*)bl2)[lane];
        for (int k = 0; k < H2; ++k)
            fma4(acc, sh1[w][k], ((const float4*)(Wl2 + (long)k * H2))[lane]);
        acc.x = fmaxf(acc.x, 0.f); acc.y = fmaxf(acc.y, 0.f);
        acc.z = fmaxf(acc.z, 0.f); acc.w = fmaxf(acc.w, 0.f);
        ((float4*)sh2[w])[lane] = acc;
    }

    {
        float sum = sh2[w][lane] * Wl3[lane]
                  + sh2[w][lane + 64] * Wl3[lane + 64]
                  + sh2[w][lane + 128] * Wl3[lane + 128]
                  + sh2[w][lane + 192] * Wl3[lane + 192];
        for (int off = 32; off; off >>= 1)
            sum += __shfl_down(sum, off);
        if (lane == 0) out[g] = sum + bl3[0];
    }
}

extern "C" void kernel_launch(void* const* d_in, const int* in_sizes, int n_in,
                              void* d_out, int out_size, void* d_ws, size_t ws_size,
                              hipStream_t stream) {
    const float* feats_node  = (const float*)d_in[0];
    const float* feats_graph = (const float*)d_in[1];
    const float* W1 = (const float*)d_in[2];
    const float* b1 = (const float*)d_in[3];
    const float* W2 = (const float*)d_in[4];
    const float* b2 = (const float*)d_in[5];
    const float* W3 = (const float*)d_in[6];
    const float* b3 = (const float*)d_in[7];
    const float* Wl1 = (const float*)d_in[8];
    const float* bl1 = (const float*)d_in[9];
    const float* Wl2 = (const float*)d_in[10];
    const float* bl2 = (const float*)d_in[11];
    const float* Wl3 = (const float*)d_in[12];
    const float* bl3 = (const float*)d_in[13];
    const int* src  = (const int*)d_in[14];
    const int* dst  = (const int*)d_in[15];
    const int* gids = (const int*)d_in[16];
    float* out = (float*)d_out;

    // workspace layout (4B units)
    float* ws = (float*)d_ws;
    float* c_out     = ws;                        // 50048
    float* c_in      = c_out + 50048;             // 50048
    float* A         = c_in + 50048;              // N*H
    float* B         = A + (size_t)NNODES * H;    // N*H
    int*   row_start = (int*)(B + (size_t)NNODES * H);  // 50176
    int*   csr_src   = row_start + 50176;         // 600000
    int*   gstart    = csr_src + NEDGES;          // 2048
    int*   partials  = gstart + 2048;             // 64
    int*   dout      = partials + 64;             // 50048
    int*   din       = dout + 50048;              // 50048
    int*   rank      = (int*)A;                   // aliases A (consumed before gather1 writes A)

    // degrees + edge ranks
    hipMemsetAsync(dout, 0, 2 * 50048 * sizeof(int), stream);
    k_deg<<<(NEDGES + 255) / 256, 256, 0, stream>>>(src, dst, dout, din, rank);

    // CSR offsets + c_in/c_out/gstart + atomic-free fill
    k_scan1<<<NB, 1024, 0, stream>>>(din, row_start, partials, c_in);
    k_scan3<<<NB, 1024, 0, stream>>>(row_start, partials, dout, c_out, gids, gstart);
    k_fill<<<(NEDGES / 4 + 255) / 256, 256, 0, stream>>>(src, dst, row_start, rank, csr_src);

    const int GEMM_GRID = (NNODES + 127) / 128;

    // layer 1
    k_gather1<<<NNODES / 4, 256, 0, stream>>>(feats_node, c_out, row_start, csr_src, A);
    k_gemm1<<<GEMM_GRID, 512, 0, stream>>>(A, c_in, c_out, W1, b1, B);

    // layer 2
    k_gather2<<<NNODES / 4, 256, 0, stream>>>(B, row_start, csr_src, A);
    k_gemm2<<<GEMM_GRID, 512, 0, stream>>>(A, c_in, c_out, W2, b2, B);

    // layer 3
    k_gather3<<<NNODES / 4, 256, 0, stream>>>(B, row_start, csr_src, A);
    k_gemm3<<<GEMM_GRID, 512, 0, stream>>>(A, c_in, c_out, W3, b3, B);

    // fused head
    k_head<<<NGRAPH / 8, 512, 0, stream>>>(B, gstart, feats_graph,
                                           Wl1, bl1, Wl2, bl2, Wl3, bl3, out);
}

// Round 11
// 377.419 us; speedup vs baseline: 1.0981x; 1.0810x over previous
//
#include <hip/hip_runtime.h>
#include <hip/hip_fp16.h>

constexpr int NNODES = 50000;
constexpr int NEDGES = 600000;
constexpr int NGRAPH = 2000;
constexpr int F0     = 64;    // IN_FEATS
constexpr int H      = 128;   // HIDDEN
constexpr int H2     = 256;   // 2*HIDDEN
constexpr int NB     = 49;    // scan blocks: 49*1024 >= 50000

static __device__ __forceinline__ void fma4(float4& acc, float s, const float4& w) {
    acc.x = fmaf(s, w.x, acc.x);
    acc.y = fmaf(s, w.y, acc.y);
    acc.z = fmaf(s, w.z, acc.z);
    acc.w = fmaf(s, w.w, acc.w);
}

// ---------------- degree count + per-edge rank (atomic-throughput floor ~55us) ----------------
__global__ void k_deg(const int* __restrict__ src, const int* __restrict__ dst,
                      int* __restrict__ dout, int* __restrict__ din,
                      int* __restrict__ rank) {
    int e = blockIdx.x * 256 + threadIdx.x;
    if (e < NEDGES) {
        int d = dst[e];
        int s = src[e];
        rank[e] = atomicAdd(&din[d], 1);
        atomicAdd(&dout[s], 1);
    }
}

// ---------------- scan phase 1: per-block scan of deg_in; also c_in ----------------
__global__ __launch_bounds__(1024) void k_scan1(const int* __restrict__ deg,
                                                int* __restrict__ row_start,
                                                int* __restrict__ partials,
                                                float* __restrict__ c_in) {
    __shared__ int wsum[16];
    int idx  = blockIdx.x * 1024 + threadIdx.x;
    int lane = threadIdx.x & 63;
    int wid  = threadIdx.x >> 6;
    int v = (idx < NNODES) ? deg[idx] : 0;
    if (idx < NNODES) c_in[idx] = rsqrtf(fmaxf((float)v, 1.0f));
    int incl = v;
#pragma unroll
    for (int off = 1; off < 64; off <<= 1) {
        int t = __shfl_up(incl, off);
        if (lane >= off) incl += t;
    }
    if (lane == 63) wsum[wid] = incl;
    __syncthreads();
    if (wid == 0) {
        int w = (lane < 16) ? wsum[lane] : 0;
        int wincl = w;
#pragma unroll
        for (int off = 1; off < 16; off <<= 1) {
            int t = __shfl_up(wincl, off);
            if (lane >= off) wincl += t;
        }
        if (lane < 16) wsum[lane] = wincl - w;
    }
    __syncthreads();
    int excl = wsum[wid] + incl - v;
    if (idx < NNODES) row_start[idx] = excl;
    if (threadIdx.x == 1023) partials[blockIdx.x] = excl + v;
}

// ---------------- scan phase 2 (fused): block offsets + sentinel + c_out + gbounds ----------------
__global__ __launch_bounds__(1024) void k_scan3(int* __restrict__ row_start,
                                                const int* __restrict__ partials,
                                                const int* __restrict__ dout,
                                                float* __restrict__ c_out,
                                                const int* __restrict__ gids,
                                                int* __restrict__ gstart) {
    __shared__ int soff[2];
    if (threadIdx.x < 64) {
        int lane = threadIdx.x;
        int v = (lane < NB) ? partials[lane] : 0;
        int incl = v;
#pragma unroll
        for (int off = 1; off < 64; off <<= 1) {
            int t = __shfl_up(incl, off);
            if (lane >= off) incl += t;
        }
        if (lane == (int)blockIdx.x) soff[0] = incl - v;
        if (lane == NB - 1) soff[1] = incl;
    }
    __syncthreads();
    int idx = blockIdx.x * 1024 + threadIdx.x;
    if (idx < NNODES) {
        row_start[idx] += soff[0];
        c_out[idx] = rsqrtf(fmaxf((float)dout[idx], 1.0f));
    } else if (idx == NNODES) {
        row_start[NNODES] = soff[1];
    }
    if (idx == 0) {
        int g0 = gids[0];
        for (int g = 0; g <= g0; ++g) gstart[g] = 0;
    } else if (idx == NNODES) {
        int gl = gids[NNODES - 1];
        for (int g = gl + 1; g <= NGRAPH; ++g) gstart[g] = NNODES;
    } else if (idx < NNODES) {
        int a = gids[idx - 1], b = gids[idx];
        for (int g = a + 1; g <= b; ++g) gstart[g] = idx;
    }
}

// ---------------- fill CSR: atomic-free (rank precomputed) ----------------
__global__ void k_fill(const int* __restrict__ src, const int* __restrict__ dst,
                       const int* __restrict__ row_start, const int* __restrict__ rank,
                       int* __restrict__ csr_src) {
    int t = blockIdx.x * 256 + threadIdx.x;
    if (t * 4 >= NEDGES) return;
    int4 s4 = ((const int4*)src)[t];
    int4 d4 = ((const int4*)dst)[t];
    int4 r4 = ((const int4*)rank)[t];
    csr_src[row_start[d4.x] + r4.x] = s4.x;
    csr_src[row_start[d4.y] + r4.y] = s4.y;
    csr_src[row_start[d4.z] + r4.z] = s4.z;
    csr_src[row_start[d4.w] + r4.w] = s4.w;
}

// ---------------- gather layer 1 (F=64 fp32 input, with c_out) ----------------
__global__ __launch_bounds__(256) void k_gather1(const float* __restrict__ x,
                                                 const float* __restrict__ c_out,
                                                 const int* __restrict__ row_start,
                                                 const int* __restrict__ csr_src,
                                                 float* __restrict__ agg) {
    int wid  = (blockIdx.x * 256 + threadIdx.x) >> 6;
    int lane = threadIdx.x & 63;
    if (wid >= NNODES) return;
    int beg = row_start[wid], end = row_start[wid + 1];
    float acc = 0.f;
    int i = beg;
    for (; i + 4 <= end; i += 4) {
        int s0 = csr_src[i + 0];
        int s1 = csr_src[i + 1];
        int s2 = csr_src[i + 2];
        int s3 = csr_src[i + 3];
        float c0 = c_out[s0], c1 = c_out[s1], c2 = c_out[s2], c3 = c_out[s3];
        float v0 = x[(long)s0 * F0 + lane];
        float v1 = x[(long)s1 * F0 + lane];
        float v2 = x[(long)s2 * F0 + lane];
        float v3 = x[(long)s3 * F0 + lane];
        acc += v0 * c0 + v1 * c1 + v2 * c2 + v3 * c3;
    }
    for (; i < end; ++i) {
        int s = csr_src[i];
        acc += x[(long)s * F0 + lane] * c_out[s];
    }
    agg[(long)wid * F0 + lane] = acc;
}

// ---------------- gather layers 2/3 (F=128, fp16 pre-scaled input) ----------------
// lane covers cols [2*lane, 2*lane+1] via one __half2 (4B) -> 256 B/row per wave.
static __device__ __forceinline__ void gather_h16_body(const __half2* __restrict__ x2,
                                                       const int* __restrict__ row_start,
                                                       const int* __restrict__ csr_src,
                                                       float* __restrict__ agg) {
    int wid  = (blockIdx.x * 256 + threadIdx.x) >> 6;
    int lane = threadIdx.x & 63;
    if (wid >= NNODES) return;
    int beg = row_start[wid], end = row_start[wid + 1];
    float2 acc = make_float2(0.f, 0.f);
    int i = beg;
    for (; i + 4 <= end; i += 4) {
        int s0 = csr_src[i + 0];
        int s1 = csr_src[i + 1];
        int s2 = csr_src[i + 2];
        int s3 = csr_src[i + 3];
        __half2 h0 = x2[(long)s0 * 64 + lane];
        __half2 h1 = x2[(long)s1 * 64 + lane];
        __half2 h2 = x2[(long)s2 * 64 + lane];
        __half2 h3 = x2[(long)s3 * 64 + lane];
        float2 f0 = __half22float2(h0);
        float2 f1 = __half22float2(h1);
        float2 f2 = __half22float2(h2);
        float2 f3 = __half22float2(h3);
        acc.x += f0.x + f1.x + f2.x + f3.x;
        acc.y += f0.y + f1.y + f2.y + f3.y;
    }
    for (; i < end; ++i) {
        int s = csr_src[i];
        float2 f = __half22float2(x2[(long)s * 64 + lane]);
        acc.x += f.x;
        acc.y += f.y;
    }
    ((float2*)agg)[(long)wid * 64 + lane] = acc;
}

__global__ __launch_bounds__(256) void k_gather2(const __half2* __restrict__ x2,
                                                 const int* __restrict__ row_start,
                                                 const int* __restrict__ csr_src,
                                                 float* __restrict__ agg) {
    gather_h16_body(x2, row_start, csr_src, agg);
}
__global__ __launch_bounds__(256) void k_gather3(const __half2* __restrict__ x2,
                                                 const int* __restrict__ row_start,
                                                 const int* __restrict__ csr_src,
                                                 float* __restrict__ agg) {
    gather_h16_body(x2, row_start, csr_src, agg);
}

// ---------------- register-blocked fused GEMM (128-row tile, 512 threads) ----------------
// out[n][j] = act( c_in[n]*(A@W)[n][j] + b[j] ) * (COSCALE ? c_out[n] : 1)
// HALFOUT: write fp16 (packed half2 x2 = 8B/thread); else fp32 float4.
template <int K, bool RELU, bool COSCALE, bool HALFOUT>
static __device__ __forceinline__ void gemm_body(const float* __restrict__ A,
                                                 const float* __restrict__ c_in,
                                                 const float* __restrict__ c_out,
                                                 const float* __restrict__ W,
                                                 const float* __restrict__ b,
                                                 void* __restrict__ out) {
    __shared__ float sW[K * H];
    for (int i = threadIdx.x; i < K * (H / 4); i += 512)
        ((float4*)sW)[i] = ((const float4*)W)[i];
    __syncthreads();

    const int c = threadIdx.x & 31;
    const int r = threadIdx.x >> 5;
    const long base = (long)blockIdx.x * 128 + r * 8;

    float4 acc[8];
#pragma unroll
    for (int i = 0; i < 8; ++i) acc[i] = make_float4(0.f, 0.f, 0.f, 0.f);

    const float4* Ap = (const float4*)A + base * (K / 4);

    for (int k4 = 0; k4 < K / 4; ++k4) {
        const float4 w0 = *(const float4*)&sW[(4 * k4 + 0) * H + 4 * c];
        const float4 w1 = *(const float4*)&sW[(4 * k4 + 1) * H + 4 * c];
        const float4 w2 = *(const float4*)&sW[(4 * k4 + 2) * H + 4 * c];
        const float4 w3 = *(const float4*)&sW[(4 * k4 + 3) * H + 4 * c];
#pragma unroll
        for (int i = 0; i < 8; ++i) {
            float4 a = Ap[(long)i * (K / 4) + k4];
            fma4(acc[i], a.x, w0);
            fma4(acc[i], a.y, w1);
            fma4(acc[i], a.z, w2);
            fma4(acc[i], a.w, w3);
        }
    }

    const float4 bv = ((const float4*)b)[c];
#pragma unroll
    for (int i = 0; i < 8; ++i) {
        long n = base + i;
        if (n < NNODES) {
            float ci = c_in[n];
            float4 res;
            res.x = fmaf(acc[i].x, ci, bv.x);
            res.y = fmaf(acc[i].y, ci, bv.y);
            res.z = fmaf(acc[i].z, ci, bv.z);
            res.w = fmaf(acc[i].w, ci, bv.w);
            if (RELU) {
                res.x = fmaxf(res.x, 0.f);
                res.y = fmaxf(res.y, 0.f);
                res.z = fmaxf(res.z, 0.f);
                res.w = fmaxf(res.w, 0.f);
            }
            if (COSCALE) {
                float co = c_out[n];
                res.x *= co; res.y *= co; res.z *= co; res.w *= co;
            }
            if (HALFOUT) {
                union { __half2 h[2]; float2 f; } u;
                u.h[0] = __floats2half2_rn(res.x, res.y);
                u.h[1] = __floats2half2_rn(res.z, res.w);
                ((float2*)out)[n * 32 + c] = u.f;
            } else {
                ((float4*)out)[n * (H / 4) + c] = res;
            }
        }
    }
}

__global__ __launch_bounds__(512) void k_gemm1(const float* __restrict__ A,
                                               const float* __restrict__ c_in,
                                               const float* __restrict__ c_out,
                                               const float* __restrict__ W,
                                               const float* __restrict__ b,
                                               void* __restrict__ out) {
    gemm_body<F0, true, true, true>(A, c_in, c_out, W, b, out);
}
__global__ __launch_bounds__(512) void k_gemm2(const float* __restrict__ A,
                                               const float* __restrict__ c_in,
                                               const float* __restrict__ c_out,
                                               const float* __restrict__ W,
                                               const float* __restrict__ b,
                                               void* __restrict__ out) {
    gemm_body<H, true, true, true>(A, c_in, c_out, W, b, out);
}
__global__ __launch_bounds__(512) void k_gemm3(const float* __restrict__ A,
                                               const float* __restrict__ c_in,
                                               const float* __restrict__ c_out,
                                               const float* __restrict__ W,
                                               const float* __restrict__ b,
                                               void* __restrict__ out) {
    gemm_body<H, false, false, false>(A, c_in, c_out, W, b, out);
}

// ---------------- fused graph head: readout mean + 3-layer MLP ----------------
__global__ __launch_bounds__(512) void k_head(const float* __restrict__ y,
                                              const int* __restrict__ gstart,
                                              const float* __restrict__ fg,
                                              const float* __restrict__ Wl1,
                                              const float* __restrict__ bl1,
                                              const float* __restrict__ Wl2,
                                              const float* __restrict__ bl2,
                                              const float* __restrict__ Wl3,
                                              const float* __restrict__ bl3,
                                              float* __restrict__ out) {
    __shared__ float smean[8][H];
    __shared__ float sh1[8][H2];
    __shared__ float sh2[8][H2];

    const int w    = threadIdx.x >> 6;
    const int lane = threadIdx.x & 63;
    const int g    = blockIdx.x * 8 + w;

    {
        int beg = gstart[g], end = gstart[g + 1];
        const float2* y2 = (const float2*)y;
        float2 acc = make_float2(0.f, 0.f);
        for (int n = beg; n < end; ++n) {
            float2 v = y2[(long)n * 64 + lane];
            acc.x += v.x;
            acc.y += v.y;
        }
        float inv = 1.0f / fmaxf((float)(end - beg), 1.0f);
        ((float2*)smean[w])[lane] = make_float2(acc.x * inv, acc.y * inv);
    }

    {
        float4 acc = ((const float4*)bl1)[lane];
        for (int k = 0; k < H; ++k)
            fma4(acc, smean[w][k], ((const float4*)(Wl1 + (long)k * H2))[lane]);
#pragma unroll
        for (int k = 0; k < 3; ++k)
            fma4(acc, fg[g * 3 + k], ((const float4*)(Wl1 + (long)(H + k) * H2))[lane]);
        acc.x = fmaxf(acc.x, 0.f); acc.y = fmaxf(acc.y, 0.f);
        acc.z = fmaxf(acc.z, 0.f); acc.w = fmaxf(acc.w, 0.f);
        ((float4*)sh1[w])[lane] = acc;
    }

    {
        float4 acc = ((const float4*)bl2)[lane];
        for (int k = 0; k < H2; ++k)
            fma4(acc, sh1[w][k], ((const float4*)(Wl2 + (long)k * H2))[lane]);
        acc.x = fmaxf(acc.x, 0.f); acc.y = fmaxf(acc.y, 0.f);
        acc.z = fmaxf(acc.z, 0.f); acc.w = fmaxf(acc.w, 0.f);
        ((float4*)sh2[w])[lane] = acc;
    }

    {
        float sum = sh2[w][lane] * Wl3[lane]
                  + sh2[w][lane + 64] * Wl3[lane + 64]
                  + sh2[w][lane + 128] * Wl3[lane + 128]
                  + sh2[w][lane + 192] * Wl3[lane + 192];
        for (int off = 32; off; off >>= 1)
            sum += __shfl_down(sum, off);
        if (lane == 0) out[g] = sum + bl3[0];
    }
}

extern "C" void kernel_launch(void* const* d_in, const int* in_sizes, int n_in,
                              void* d_out, int out_size, void* d_ws, size_t ws_size,
                              hipStream_t stream) {
    const float* feats_node  = (const float*)d_in[0];
    const float* feats_graph = (const float*)d_in[1];
    const float* W1 = (const float*)d_in[2];
    const float* b1 = (const float*)d_in[3];
    const float* W2 = (const float*)d_in[4];
    const float* b2 = (const float*)d_in[5];
    const float* W3 = (const float*)d_in[6];
    const float* b3 = (const float*)d_in[7];
    const float* Wl1 = (const float*)d_in[8];
    const float* bl1 = (const float*)d_in[9];
    const float* Wl2 = (const float*)d_in[10];
    const float* bl2 = (const float*)d_in[11];
    const float* Wl3 = (const float*)d_in[12];
    const float* bl3 = (const float*)d_in[13];
    const int* src  = (const int*)d_in[14];
    const int* dst  = (const int*)d_in[15];
    const int* gids = (const int*)d_in[16];
    float* out = (float*)d_out;

    // workspace layout (4B units)
    float* ws = (float*)d_ws;
    float* c_out     = ws;                        // 50048
    float* c_in      = c_out + 50048;             // 50048
    float* A         = c_in + 50048;              // N*H fp32
    float* B         = A + (size_t)NNODES * H;    // N*H fp32 (gemm3 out); fp16 B16 aliases it
    int*   row_start = (int*)(B + (size_t)NNODES * H);  // 50176
    int*   csr_src   = row_start + 50176;         // 600000
    int*   gstart    = csr_src + NEDGES;          // 2048
    int*   partials  = gstart + 2048;             // 64
    int*   dout      = partials + 64;             // 50048
    int*   din       = dout + 50048;              // 50048
    int*   rank      = (int*)A;                   // aliases A (consumed before gather1 writes A)
    __half2* B16     = (__half2*)B;               // fp16 view (dead before gemm3's fp32 write)

    // degrees + edge ranks
    hipMemsetAsync(dout, 0, 2 * 50048 * sizeof(int), stream);
    k_deg<<<(NEDGES + 255) / 256, 256, 0, stream>>>(src, dst, dout, din, rank);

    // CSR offsets + c_in/c_out/gstart + atomic-free fill
    k_scan1<<<NB, 1024, 0, stream>>>(din, row_start, partials, c_in);
    k_scan3<<<NB, 1024, 0, stream>>>(row_start, partials, dout, c_out, gids, gstart);
    k_fill<<<(NEDGES / 4 + 255) / 256, 256, 0, stream>>>(src, dst, row_start, rank, csr_src);

    const int GEMM_GRID = (NNODES + 127) / 128;

    // layer 1: fp32 gather, gemm writes fp16 (pre-scaled by c_out)
    k_gather1<<<NNODES / 4, 256, 0, stream>>>(feats_node, c_out, row_start, csr_src, A);
    k_gemm1<<<GEMM_GRID, 512, 0, stream>>>(A, c_in, c_out, W1, b1, B16);

    // layer 2: fp16 gather, gemm writes fp16 (pre-scaled)
    k_gather2<<<NNODES / 4, 256, 0, stream>>>(B16, row_start, csr_src, A);
    k_gemm2<<<GEMM_GRID, 512, 0, stream>>>(A, c_in, c_out, W2, b2, B16);

    // layer 3: fp16 gather, gemm writes fp32 (final y_nodes)
    k_gather3<<<NNODES / 4, 256, 0, stream>>>(B16, row_start, csr_src, A);
    k_gemm3<<<GEMM_GRID, 512, 0, stream>>>(A, c_in, c_out, W3, b3, B);

    // fused head
    k_head<<<NGRAPH / 8, 512, 0, stream>>>(B, gstart, feats_graph,
                                           Wl1, bl1, Wl2, bl2, Wl3, bl3, out);
}

// Round 12
// 371.003 us; speedup vs baseline: 1.1171x; 1.0173x over previous
//
#include <hip/hip_runtime.h>
#include <hip/hip_fp16.h>

constexpr int NNODES = 50000;
constexpr int NEDGES = 600000;
constexpr int NGRAPH = 2000;
constexpr int F0     = 64;    // IN_FEATS
constexpr int H      = 128;   // HIDDEN
constexpr int H2     = 256;   // 2*HIDDEN
constexpr int NB     = 49;    // scan blocks: 49*1024 >= 50000
constexpr int DEG_THREADS = ((NEDGES + 255) / 256) * 256;  // 600064

static __device__ __forceinline__ void fma4(float4& acc, float s, const float4& w) {
    acc.x = fmaf(s, w.x, acc.x);
    acc.y = fmaf(s, w.y, acc.y);
    acc.z = fmaf(s, w.z, acc.z);
    acc.w = fmaf(s, w.w, acc.w);
}

// ---------------- degree count + per-edge rank + fused feats->fp16 cast ----------------
// The 1.2M atomics leave VALU/HBM idle (VALUBusy 0.3%, HBM 10%); the 19 MB
// conversion hides entirely under the atomic shadow.
__global__ void k_deg(const int* __restrict__ src, const int* __restrict__ dst,
                      int* __restrict__ dout, int* __restrict__ din,
                      int* __restrict__ rank,
                      const float2* __restrict__ feats2, __half2* __restrict__ feats16) {
    int e = blockIdx.x * 256 + threadIdx.x;
    if (e < NEDGES) {
        int d = dst[e];
        int s = src[e];
        rank[e] = atomicAdd(&din[d], 1);
        atomicAdd(&dout[s], 1);
    }
    for (int j = blockIdx.x * 256 + threadIdx.x; j < NNODES * (F0 / 2); j += DEG_THREADS) {
        float2 f = feats2[j];
        feats16[j] = __floats2half2_rn(f.x, f.y);
    }
}

// ---------------- scan phase 1: per-block scan of deg_in; also c_in ----------------
__global__ __launch_bounds__(1024) void k_scan1(const int* __restrict__ deg,
                                                int* __restrict__ row_start,
                                                int* __restrict__ partials,
                                                float* __restrict__ c_in) {
    __shared__ int wsum[16];
    int idx  = blockIdx.x * 1024 + threadIdx.x;
    int lane = threadIdx.x & 63;
    int wid  = threadIdx.x >> 6;
    int v = (idx < NNODES) ? deg[idx] : 0;
    if (idx < NNODES) c_in[idx] = rsqrtf(fmaxf((float)v, 1.0f));
    int incl = v;
#pragma unroll
    for (int off = 1; off < 64; off <<= 1) {
        int t = __shfl_up(incl, off);
        if (lane >= off) incl += t;
    }
    if (lane == 63) wsum[wid] = incl;
    __syncthreads();
    if (wid == 0) {
        int w = (lane < 16) ? wsum[lane] : 0;
        int wincl = w;
#pragma unroll
        for (int off = 1; off < 16; off <<= 1) {
            int t = __shfl_up(wincl, off);
            if (lane >= off) wincl += t;
        }
        if (lane < 16) wsum[lane] = wincl - w;
    }
    __syncthreads();
    int excl = wsum[wid] + incl - v;
    if (idx < NNODES) row_start[idx] = excl;
    if (threadIdx.x == 1023) partials[blockIdx.x] = excl + v;
}

// ---------------- scan phase 2 (fused): block offsets + sentinel + c_out + gbounds ----------------
__global__ __launch_bounds__(1024) void k_scan3(int* __restrict__ row_start,
                                                const int* __restrict__ partials,
                                                const int* __restrict__ dout,
                                                float* __restrict__ c_out,
                                                const int* __restrict__ gids,
                                                int* __restrict__ gstart) {
    __shared__ int soff[2];
    if (threadIdx.x < 64) {
        int lane = threadIdx.x;
        int v = (lane < NB) ? partials[lane] : 0;
        int incl = v;
#pragma unroll
        for (int off = 1; off < 64; off <<= 1) {
            int t = __shfl_up(incl, off);
            if (lane >= off) incl += t;
        }
        if (lane == (int)blockIdx.x) soff[0] = incl - v;
        if (lane == NB - 1) soff[1] = incl;
    }
    __syncthreads();
    int idx = blockIdx.x * 1024 + threadIdx.x;
    if (idx < NNODES) {
        row_start[idx] += soff[0];
        c_out[idx] = rsqrtf(fmaxf((float)dout[idx], 1.0f));
    } else if (idx == NNODES) {
        row_start[NNODES] = soff[1];
    }
    if (idx == 0) {
        int g0 = gids[0];
        for (int g = 0; g <= g0; ++g) gstart[g] = 0;
    } else if (idx == NNODES) {
        int gl = gids[NNODES - 1];
        for (int g = gl + 1; g <= NGRAPH; ++g) gstart[g] = NNODES;
    } else if (idx < NNODES) {
        int a = gids[idx - 1], b = gids[idx];
        for (int g = a + 1; g <= b; ++g) gstart[g] = idx;
    }
}

// ---------------- fill CSR: atomic-free (rank precomputed) ----------------
__global__ void k_fill(const int* __restrict__ src, const int* __restrict__ dst,
                       const int* __restrict__ row_start, const int* __restrict__ rank,
                       int* __restrict__ csr_src) {
    int t = blockIdx.x * 256 + threadIdx.x;
    if (t * 4 >= NEDGES) return;
    int4 s4 = ((const int4*)src)[t];
    int4 d4 = ((const int4*)dst)[t];
    int4 r4 = ((const int4*)rank)[t];
    csr_src[row_start[d4.x] + r4.x] = s4.x;
    csr_src[row_start[d4.y] + r4.y] = s4.y;
    csr_src[row_start[d4.z] + r4.z] = s4.z;
    csr_src[row_start[d4.w] + r4.w] = s4.w;
}

// ---------------- gather layer 1 (F=64 fp16 feats, c_out per edge) ----------------
// one 32-lane group per node; lane q covers cols [2q, 2q+1] via one __half2.
__global__ __launch_bounds__(256) void k_gather1(const __half2* __restrict__ x2,
                                                 const float* __restrict__ c_out,
                                                 const int* __restrict__ row_start,
                                                 const int* __restrict__ csr_src,
                                                 float* __restrict__ agg) {
    int wid = (blockIdx.x * 256 + threadIdx.x) >> 5;
    int q   = threadIdx.x & 31;
    if (wid >= NNODES) return;
    int beg = row_start[wid], end = row_start[wid + 1];
    float2 acc = make_float2(0.f, 0.f);
    int i = beg;
    for (; i + 4 <= end; i += 4) {
        int s0 = csr_src[i + 0];
        int s1 = csr_src[i + 1];
        int s2 = csr_src[i + 2];
        int s3 = csr_src[i + 3];
        float c0 = c_out[s0], c1 = c_out[s1], c2 = c_out[s2], c3 = c_out[s3];
        float2 f0 = __half22float2(x2[(long)s0 * 32 + q]);
        float2 f1 = __half22float2(x2[(long)s1 * 32 + q]);
        float2 f2 = __half22float2(x2[(long)s2 * 32 + q]);
        float2 f3 = __half22float2(x2[(long)s3 * 32 + q]);
        acc.x += f0.x * c0 + f1.x * c1 + f2.x * c2 + f3.x * c3;
        acc.y += f0.y * c0 + f1.y * c1 + f2.y * c2 + f3.y * c3;
    }
    for (; i < end; ++i) {
        int s = csr_src[i];
        float co = c_out[s];
        float2 f = __half22float2(x2[(long)s * 32 + q]);
        acc.x += f.x * co;
        acc.y += f.y * co;
    }
    ((float2*)agg)[(long)wid * 32 + q] = acc;
}

// ---------------- gather layers 2/3 (F=128, fp16 pre-scaled input) ----------------
static __device__ __forceinline__ void gather_h16_body(const __half2* __restrict__ x2,
                                                       const int* __restrict__ row_start,
                                                       const int* __restrict__ csr_src,
                                                       float* __restrict__ agg) {
    int wid  = (blockIdx.x * 256 + threadIdx.x) >> 6;
    int lane = threadIdx.x & 63;
    if (wid >= NNODES) return;
    int beg = row_start[wid], end = row_start[wid + 1];
    float2 acc = make_float2(0.f, 0.f);
    int i = beg;
    for (; i + 4 <= end; i += 4) {
        int s0 = csr_src[i + 0];
        int s1 = csr_src[i + 1];
        int s2 = csr_src[i + 2];
        int s3 = csr_src[i + 3];
        float2 f0 = __half22float2(x2[(long)s0 * 64 + lane]);
        float2 f1 = __half22float2(x2[(long)s1 * 64 + lane]);
        float2 f2 = __half22float2(x2[(long)s2 * 64 + lane]);
        float2 f3 = __half22float2(x2[(long)s3 * 64 + lane]);
        acc.x += f0.x + f1.x + f2.x + f3.x;
        acc.y += f0.y + f1.y + f2.y + f3.y;
    }
    for (; i < end; ++i) {
        int s = csr_src[i];
        float2 f = __half22float2(x2[(long)s * 64 + lane]);
        acc.x += f.x;
        acc.y += f.y;
    }
    ((float2*)agg)[(long)wid * 64 + lane] = acc;
}

__global__ __launch_bounds__(256) void k_gather2(const __half2* __restrict__ x2,
                                                 const int* __restrict__ row_start,
                                                 const int* __restrict__ csr_src,
                                                 float* __restrict__ agg) {
    gather_h16_body(x2, row_start, csr_src, agg);
}
__global__ __launch_bounds__(256) void k_gather3(const __half2* __restrict__ x2,
                                                 const int* __restrict__ row_start,
                                                 const int* __restrict__ csr_src,
                                                 float* __restrict__ agg) {
    gather_h16_body(x2, row_start, csr_src, agg);
}

// ---------------- register-blocked fused GEMM (128-row tile, 512 threads) ----------------
// out[n][j] = act( c_in[n]*(A@W)[n][j] + b[j] ) * (COSCALE ? c_out[n] : 1)
template <int K, bool RELU, bool COSCALE, bool HALFOUT>
static __device__ __forceinline__ void gemm_body(const float* __restrict__ A,
                                                 const float* __restrict__ c_in,
                                                 const float* __restrict__ c_out,
                                                 const float* __restrict__ W,
                                                 const float* __restrict__ b,
                                                 void* __restrict__ out) {
    __shared__ float sW[K * H];
    for (int i = threadIdx.x; i < K * (H / 4); i += 512)
        ((float4*)sW)[i] = ((const float4*)W)[i];
    __syncthreads();

    const int c = threadIdx.x & 31;
    const int r = threadIdx.x >> 5;
    const long base = (long)blockIdx.x * 128 + r * 8;

    float4 acc[8];
#pragma unroll
    for (int i = 0; i < 8; ++i) acc[i] = make_float4(0.f, 0.f, 0.f, 0.f);

    const float4* Ap = (const float4*)A + base * (K / 4);

    for (int k4 = 0; k4 < K / 4; ++k4) {
        const float4 w0 = *(const float4*)&sW[(4 * k4 + 0) * H + 4 * c];
        const float4 w1 = *(const float4*)&sW[(4 * k4 + 1) * H + 4 * c];
        const float4 w2 = *(const float4*)&sW[(4 * k4 + 2) * H + 4 * c];
        const float4 w3 = *(const float4*)&sW[(4 * k4 + 3) * H + 4 * c];
#pragma unroll
        for (int i = 0; i < 8; ++i) {
            float4 a = Ap[(long)i * (K / 4) + k4];
            fma4(acc[i], a.x, w0);
            fma4(acc[i], a.y, w1);
            fma4(acc[i], a.z, w2);
            fma4(acc[i], a.w, w3);
        }
    }

    const float4 bv = ((const float4*)b)[c];
#pragma unroll
    for (int i = 0; i < 8; ++i) {
        long n = base + i;
        if (n < NNODES) {
            float ci = c_in[n];
            float4 res;
            res.x = fmaf(acc[i].x, ci, bv.x);
            res.y = fmaf(acc[i].y, ci, bv.y);
            res.z = fmaf(acc[i].z, ci, bv.z);
            res.w = fmaf(acc[i].w, ci, bv.w);
            if (RELU) {
                res.x = fmaxf(res.x, 0.f);
                res.y = fmaxf(res.y, 0.f);
                res.z = fmaxf(res.z, 0.f);
                res.w = fmaxf(res.w, 0.f);
            }
            if (COSCALE) {
                float co = c_out[n];
                res.x *= co; res.y *= co; res.z *= co; res.w *= co;
            }
            if (HALFOUT) {
                union { __half2 h[2]; float2 f; } u;
                u.h[0] = __floats2half2_rn(res.x, res.y);
                u.h[1] = __floats2half2_rn(res.z, res.w);
                ((float2*)out)[n * 32 + c] = u.f;
            } else {
                ((float4*)out)[n * (H / 4) + c] = res;
            }
        }
    }
}

__global__ __launch_bounds__(512) void k_gemm1(const float* __restrict__ A,
                                               const float* __restrict__ c_in,
                                               const float* __restrict__ c_out,
                                               const float* __restrict__ W,
                                               const float* __restrict__ b,
                                               void* __restrict__ out) {
    gemm_body<F0, true, true, true>(A, c_in, c_out, W, b, out);
}
__global__ __launch_bounds__(512) void k_gemm2(const float* __restrict__ A,
                                               const float* __restrict__ c_in,
                                               const float* __restrict__ c_out,
                                               const float* __restrict__ W,
                                               const float* __restrict__ b,
                                               void* __restrict__ out) {
    gemm_body<H, true, true, true>(A, c_in, c_out, W, b, out);
}
__global__ __launch_bounds__(512) void k_gemm3(const float* __restrict__ A,
                                               const float* __restrict__ c_in,
                                               const float* __restrict__ c_out,
                                               const float* __restrict__ W,
                                               const float* __restrict__ b,
                                               void* __restrict__ out) {
    gemm_body<H, false, false, false>(A, c_in, c_out, W, b, out);
}

// ---------------- fused graph head: readout mean + 3-layer MLP ----------------
__global__ __launch_bounds__(512) void k_head(const float* __restrict__ y,
                                              const int* __restrict__ gstart,
                                              const float* __restrict__ fg,
                                              const float* __restrict__ Wl1,
                                              const float* __restrict__ bl1,
                                              const float* __restrict__ Wl2,
                                              const float* __restrict__ bl2,
                                              const float* __restrict__ Wl3,
                                              const float* __restrict__ bl3,
                                              float* __restrict__ out) {
    __shared__ float smean[8][H];
    __shared__ float sh1[8][H2];
    __shared__ float sh2[8][H2];

    const int w    = threadIdx.x >> 6;
    const int lane = threadIdx.x & 63;
    const int g    = blockIdx.x * 8 + w;

    {
        int beg = gstart[g], end = gstart[g + 1];
        const float2* y2 = (const float2*)y;
        float2 acc = make_float2(0.f, 0.f);
        for (int n = beg; n < end; ++n) {
            float2 v = y2[(long)n * 64 + lane];
            acc.x += v.x;
            acc.y += v.y;
        }
        float inv = 1.0f / fmaxf((float)(end - beg), 1.0f);
        ((float2*)smean[w])[lane] = make_float2(acc.x * inv, acc.y * inv);
    }

    {
        float4 acc = ((const float4*)bl1)[lane];
        for (int k = 0; k < H; ++k)
            fma4(acc, smean[w][k], ((const float4*)(Wl1 + (long)k * H2))[lane]);
#pragma unroll
        for (int k = 0; k < 3; ++k)
            fma4(acc, fg[g * 3 + k], ((const float4*)(Wl1 + (long)(H + k) * H2))[lane]);
        acc.x = fmaxf(acc.x, 0.f); acc.y = fmaxf(acc.y, 0.f);
        acc.z = fmaxf(acc.z, 0.f); acc.w = fmaxf(acc.w, 0.f);
        ((float4*)sh1[w])[lane] = acc;
    }

    {
        float4 acc = ((const float4*)bl2)[lane];
        for (int k = 0; k < H2; ++k)
            fma4(acc, sh1[w][k], ((const float4*)(Wl2 + (long)k * H2))[lane]);
        acc.x = fmaxf(acc.x, 0.f); acc.y = fmaxf(acc.y, 0.f);
        acc.z = fmaxf(acc.z, 0.f); acc.w = fmaxf(acc.w, 0.f);
        ((float4*)sh2[w])[lane] = acc;
    }

    {
        float sum = sh2[w][lane] * Wl3[lane]
                  + sh2[w][lane + 64] * Wl3[lane + 64]
                  + sh2[w][lane + 128] * Wl3[lane + 128]
                  + sh2[w][lane + 192] * Wl3[lane + 192];
        for (int off = 32; off; off >>= 1)
            sum += __shfl_down(sum, off);
        if (lane == 0) out[g] = sum + bl3[0];
    }
}

extern "C" void kernel_launch(void* const* d_in, const int* in_sizes, int n_in,
                              void* d_out, int out_size, void* d_ws, size_t ws_size,
                              hipStream_t stream) {
    const float* feats_node  = (const float*)d_in[0];
    const float* feats_graph = (const float*)d_in[1];
    const float* W1 = (const float*)d_in[2];
    const float* b1 = (const float*)d_in[3];
    const float* W2 = (const float*)d_in[4];
    const float* b2 = (const float*)d_in[5];
    const float* W3 = (const float*)d_in[6];
    const float* b3 = (const float*)d_in[7];
    const float* Wl1 = (const float*)d_in[8];
    const float* bl1 = (const float*)d_in[9];
    const float* Wl2 = (const float*)d_in[10];
    const float* bl2 = (const float*)d_in[11];
    const float* Wl3 = (const float*)d_in[12];
    const float* bl3 = (const float*)d_in[13];
    const int* src  = (const int*)d_in[14];
    const int* dst  = (const int*)d_in[15];
    const int* gids = (const int*)d_in[16];
    float* out = (float*)d_out;

    // workspace layout (4B units)
    float* ws = (float*)d_ws;
    float* c_out     = ws;                        // 50048
    float* c_in      = c_out + 50048;             // 50048
    float* A         = c_in + 50048;              // N*H fp32
    float* B         = A + (size_t)NNODES * H;    // N*H fp32 (gemm3 out); fp16 B16 aliases it
    int*   row_start = (int*)(B + (size_t)NNODES * H);  // 50176
    int*   csr_src   = row_start + 50176;         // 600000
    int*   gstart    = csr_src + NEDGES;          // 2048
    int*   partials  = gstart + 2048;             // 64
    int*   dout      = partials + 64;             // 50048
    int*   din       = dout + 50048;              // 50048
    __half2* feats16 = (__half2*)(din + 50048);   // N*32 half2 = 1.6M 4B-units
    int*   rank      = (int*)A;                   // aliases A (consumed before gather1 writes A)
    __half2* B16     = (__half2*)B;               // fp16 view (dead before gemm3's fp32 write)

    // degrees + edge ranks + fused feats->fp16 cast
    hipMemsetAsync(dout, 0, 2 * 50048 * sizeof(int), stream);
    k_deg<<<(NEDGES + 255) / 256, 256, 0, stream>>>(src, dst, dout, din, rank,
                                                    (const float2*)feats_node, feats16);

    // CSR offsets + c_in/c_out/gstart + atomic-free fill
    k_scan1<<<NB, 1024, 0, stream>>>(din, row_start, partials, c_in);
    k_scan3<<<NB, 1024, 0, stream>>>(row_start, partials, dout, c_out, gids, gstart);
    k_fill<<<(NEDGES / 4 + 255) / 256, 256, 0, stream>>>(src, dst, row_start, rank, csr_src);

    const int GEMM_GRID = (NNODES + 127) / 128;

    // layer 1: fp16 gather (32 lanes/node), gemm writes fp16 (pre-scaled by c_out)
    k_gather1<<<(NNODES * 32 + 255) / 256, 256, 0, stream>>>(feats16, c_out, row_start, csr_src, A);
    k_gemm1<<<GEMM_GRID, 512, 0, stream>>>(A, c_in, c_out, W1, b1, B16);

    // layer 2: fp16 gather, gemm writes fp16 (pre-scaled)
    k_gather2<<<NNODES / 4, 256, 0, stream>>>(B16, row_start, csr_src, A);
    k_gemm2<<<GEMM_GRID, 512, 0, stream>>>(A, c_in, c_out, W2, b2, B16);

    // layer 3: fp16 gather, gemm writes fp32 (final y_nodes)
    k_gather3<<<NNODES / 4, 256, 0, stream>>>(B16, row_start, csr_src, A);
    k_gemm3<<<GEMM_GRID, 512, 0, stream>>>(A, c_in, c_out, W3, b3, B);

    // fused head
    k_head<<<NGRAPH / 8, 512, 0, stream>>>(B, gstart, feats_graph,
                                           Wl1, bl1, Wl2, bl2, Wl3, bl3, out);
}